// Round 6
// baseline (716.116 us; speedup 1.0000x reference)
//
#include <hip/hip_runtime.h>
#include <math.h>

#define EMB 256
#define HEADS 8
#define HD 32
#define BATCH 2
#define SEQ 4096
#define QSCALE 0.25504672075827703f   // (1/sqrt(32)) * log2(e)  -- exp2-folded softmax scale

typedef __attribute__((ext_vector_type(8))) _Float16 f16x8;
typedef __attribute__((ext_vector_type(4))) _Float16 f16x4;
typedef __attribute__((ext_vector_type(2))) __fp16 fp16x2_native;
typedef __attribute__((ext_vector_type(4))) float f32x4;
typedef unsigned int uint_t;

__device__ __forceinline__ uint_t pk16(float a, float b) {
    union { fp16x2_native h; uint_t u; } cv;
    cv.h = __builtin_amdgcn_cvt_pkrtz(a, b);
    return cv.u;
}

#define MFMA16(A, B, C) __builtin_amdgcn_mfma_f32_16x16x32_f16(A, B, C, 0, 0, 0)

// ---------------------------------------------------------------------------
// Prep 1: query fp32 -> Xh/Xl fp16 hi/lo split.  [r=b*4096+s][256]
// ---------------------------------------------------------------------------
__global__ __launch_bounds__(256) void prep_x_kernel(
    const float* __restrict__ q, _Float16* __restrict__ Xh, _Float16* __restrict__ Xl)
{
    const int i = (blockIdx.x * 256 + threadIdx.x) * 8;
    float4 v0 = *(const float4*)(q + i);
    float4 v1 = *(const float4*)(q + i + 4);
    float xs[8] = {v0.x, v0.y, v0.z, v0.w, v1.x, v1.y, v1.z, v1.w};
    f16x8 hv, lv;
    #pragma unroll
    for (int j = 0; j < 8; j++) {
        _Float16 h = (_Float16)xs[j];
        hv[j] = h;
        lv[j] = (_Float16)(xs[j] - (float)h);
    }
    *(f16x8*)(Xh + i) = hv;
    *(f16x8*)(Xl + i) = lv;
}

// ---------------------------------------------------------------------------
// Prep 2: weights -> transposed fp16 hi/lo.
//   Wth/Wtl: [p][h][e=32][d=256], QSCALE folded into p==0 (Wq)
//   WoTh/WoTl: [o=256][he=256]
// ---------------------------------------------------------------------------
__global__ __launch_bounds__(256) void prep_w_kernel(
    const float* __restrict__ wq, const float* __restrict__ wk,
    const float* __restrict__ wv, const float* __restrict__ wo,
    _Float16* __restrict__ Wth, _Float16* __restrict__ Wtl,
    _Float16* __restrict__ WoTh, _Float16* __restrict__ WoTl)
{
    for (int t = blockIdx.x * 256 + threadIdx.x; t < 262144; t += 256 * 256) {
        if (t < 196608) {
            int d = t & 255, e = (t >> 8) & 31, ph = t >> 13;
            int p = ph >> 3, h = ph & 7;
            const float* w = (p == 0) ? wq : (p == 1 ? wk : wv);
            float val = w[h * 8192 + d * 32 + e] * ((p == 0) ? QSCALE : 1.0f);
            _Float16 hi = (_Float16)val;
            Wth[t] = hi;
            Wtl[t] = (_Float16)(val - (float)hi);
        } else {
            int t2 = t - 196608;
            int he = t2 & 255, o = t2 >> 8;
            float val = wo[(he >> 5) * 8192 + (he & 31) * 256 + o];
            _Float16 hi = (_Float16)val;
            WoTh[t2] = hi;
            WoTl[t2] = (_Float16)(val - (float)hi);
        }
    }
}

// ---------------------------------------------------------------------------
// Kernel 1: QKV projection as MFMA GEMM, no LDS staging of operands.
// grid (128, 24): x = 64-row tile (wave = 16 rows), y = p*8+h.
// D[s][e] = Xh*Wh + Xl*Wh + Xh*Wl   (fp32-grade via hi/lo split)
// Q/K: LDS-staged 64B-row writes.  V: direct VT[e][s] f16x4 writes.
// ---------------------------------------------------------------------------
__global__ __launch_bounds__(256) void qkv_gemm_kernel(
    const _Float16* __restrict__ Xh, const _Float16* __restrict__ Xl,
    const _Float16* __restrict__ Wth, const _Float16* __restrict__ Wtl,
    _Float16* __restrict__ Qf, _Float16* __restrict__ Kf, _Float16* __restrict__ VT)
{
    __shared__ _Float16 st[4][16][32];
    const int t = threadIdx.x, w = t >> 6, l = t & 63, lo4 = l & 15, g = l >> 4;
    const int tile = blockIdx.x, ph = blockIdx.y, p = ph >> 3, h = ph & 7;
    const int r0 = tile * 64 + w * 16;
    const int b = (tile * 64) >> 12;
    const int s_base = (tile * 64) & (SEQ - 1);
    const int hb = h * BATCH + b;

    f16x8 Ah[8], Al[8];
    const size_t xoff = (size_t)(r0 + lo4) * 256 + g * 8;
    #pragma unroll
    for (int kc = 0; kc < 8; kc++) {
        Ah[kc] = *(const f16x8*)(Xh + xoff + kc * 32);
        Al[kc] = *(const f16x8*)(Xl + xoff + kc * 32);
    }

    f32x4 D[2];
    #pragma unroll
    for (int ct = 0; ct < 2; ct++) {
        f32x4 acc = {0.f, 0.f, 0.f, 0.f};
        const size_t woff = (size_t)(ph * 32 + ct * 16 + lo4) * 256 + g * 8;
        #pragma unroll
        for (int kc = 0; kc < 8; kc++) {
            f16x8 Bh = *(const f16x8*)(Wth + woff + kc * 32);
            f16x8 Bl = *(const f16x8*)(Wtl + woff + kc * 32);
            acc = MFMA16(Ah[kc], Bh, acc);
            acc = MFMA16(Al[kc], Bh, acc);
            acc = MFMA16(Ah[kc], Bl, acc);
        }
        D[ct] = acc;
    }

    if (p < 2) {
        #pragma unroll
        for (int ct = 0; ct < 2; ct++)
            #pragma unroll
            for (int r = 0; r < 4; r++)
                st[w][g * 4 + r][ct * 16 + lo4] = (_Float16)D[ct][r];
        __syncthreads();
        _Float16* dst = (p == 0) ? Qf : Kf;
        const int rl = t >> 2, e8 = (t & 3) * 8;   // rl = 0..63 local row
        *(f16x8*)(dst + ((size_t)hb * SEQ + s_base + rl) * HD + e8) =
            *(f16x8*)&st[rl >> 4][rl & 15][e8];
    } else {
        #pragma unroll
        for (int ct = 0; ct < 2; ct++) {
            f16x4 v;
            #pragma unroll
            for (int r = 0; r < 4; r++) v[r] = (_Float16)D[ct][r];
            *(f16x4*)(VT + ((size_t)hb * HD + ct * 16 + lo4) * SEQ + s_base + w * 16 + g * 4) = v;
        }
    }
}

// ---------------------------------------------------------------------------
// Kernel 2: fused attention, two-pass no-max softmax (exp2-domain), fp16 MFMA.
// Round-13: round-0 schedule UNTOUCHED (5 rescheduling attempts all
// regressed; the compiler's order is locally optimal).  ONE structural
// change: q-tile 32 -> 64 rows/block (1024 blocks).  Each block reads
// K twice + V once (768 KB); the 1.07 GB streaming P-write flood evicts
// K/V from the 4MB/XCD L2, so those reads largely miss to HBM.  Doubling
// q-rows per block HALVES the total K/V re-read volume (1.57 -> 0.79 GB).
// Implemented as 4 q-fragments (Bq0..Bq3), the round-0 shuffle-network/PV
// pattern replicated per fragment; Hred LDS reused across two epilogue
// rounds so LDS stays at round-0 size.
// ---------------------------------------------------------------------------
__global__ __launch_bounds__(256) void attn_kernel(
    const _Float16* __restrict__ Qf, const _Float16* __restrict__ Kf,
    const _Float16* __restrict__ VT,
    float* __restrict__ attn_out,     // [hb][q][k]
    _Float16* __restrict__ heads)     // [hb][q][e] fp16
{
    __shared__ float lred[4][4][16];
    __shared__ float Hred[4][32][33];

    const int tid = threadIdx.x;
    const int w = tid >> 6;
    const int l = tid & 63;
    const int lo4 = l & 15;
    const int g = l >> 4;
    // XCD swizzle: 1024 blocks = 16 hb x 64 qtiles; hb%8 == bid%8 == XCD
    const int bid = blockIdx.x;
    const int xcd = bid & 7;
    const int j = bid >> 3;
    const int hb = xcd + 8 * (j >> 6);
    const int q0 = (j & 63) * 64;

    const _Float16* Qb = Qf + (size_t)hb * SEQ * HD;
    const _Float16* Kb = Kf + (size_t)hb * SEQ * HD;
    const _Float16* Vb = VT + (size_t)hb * HD * SEQ;

    const f16x8 Bq0 = *(const f16x8*)(Qb + (size_t)(q0 + lo4) * HD + g * 8);
    const f16x8 Bq1 = *(const f16x8*)(Qb + (size_t)(q0 + 16 + lo4) * HD + g * 8);
    const f16x8 Bq2 = *(const f16x8*)(Qb + (size_t)(q0 + 32 + lo4) * HD + g * 8);
    const f16x8 Bq3 = *(const f16x8*)(Qb + (size_t)(q0 + 48 + lo4) * HD + g * 8);

    const int c_lo = w * 32, c_hi = c_lo + 32;   // contiguous per-wave k-range

    // ---------- pass A: row sums of exp2(s) ----------
    float ls0 = 0.f, ls1 = 0.f, ls2 = 0.f, ls3 = 0.f;
    for (int c = c_lo; c < c_hi; c++) {
        const int k0 = c * 32;
        #pragma unroll
        for (int s = 0; s < 2; s++) {
            f16x8 Ak = *(const f16x8*)(Kb + (size_t)(k0 + s * 16 + lo4) * HD + g * 8);
            f32x4 Z = {0.f, 0.f, 0.f, 0.f};
            f32x4 D0 = MFMA16(Ak, Bq0, Z);
            f32x4 D1 = MFMA16(Ak, Bq1, Z);
            f32x4 D2 = MFMA16(Ak, Bq2, Z);
            f32x4 D3 = MFMA16(Ak, Bq3, Z);
            ls0 += exp2f(D0[0]) + exp2f(D0[1]) + exp2f(D0[2]) + exp2f(D0[3]);
            ls1 += exp2f(D1[0]) + exp2f(D1[1]) + exp2f(D1[2]) + exp2f(D1[3]);
            ls2 += exp2f(D2[0]) + exp2f(D2[1]) + exp2f(D2[2]) + exp2f(D2[3]);
            ls3 += exp2f(D3[0]) + exp2f(D3[1]) + exp2f(D3[2]) + exp2f(D3[3]);
        }
    }
    ls0 += __shfl_xor(ls0, 16, 64); ls0 += __shfl_xor(ls0, 32, 64);
    ls1 += __shfl_xor(ls1, 16, 64); ls1 += __shfl_xor(ls1, 32, 64);
    ls2 += __shfl_xor(ls2, 16, 64); ls2 += __shfl_xor(ls2, 32, 64);
    ls3 += __shfl_xor(ls3, 16, 64); ls3 += __shfl_xor(ls3, 32, 64);
    if (l < 16) {
        lred[w][0][lo4] = ls0; lred[w][1][lo4] = ls1;
        lred[w][2][lo4] = ls2; lred[w][3][lo4] = ls3;
    }
    __syncthreads();
    const float inv0 = 1.0f / (lred[0][0][lo4] + lred[1][0][lo4] + lred[2][0][lo4] + lred[3][0][lo4]);
    const float inv1 = 1.0f / (lred[0][1][lo4] + lred[1][1][lo4] + lred[2][1][lo4] + lred[3][1][lo4]);
    const float inv2 = 1.0f / (lred[0][2][lo4] + lred[1][2][lo4] + lred[2][2][lo4] + lred[3][2][lo4]);
    const float inv3 = 1.0f / (lred[0][3][lo4] + lred[1][3][lo4] + lred[2][3][lo4] + lred[3][3][lo4]);

    // ---------- pass B: recompute, write probs, PV ----------
    f32x4 H00 = {0.f,0.f,0.f,0.f}, H01 = {0.f,0.f,0.f,0.f};
    f32x4 H10 = {0.f,0.f,0.f,0.f}, H11 = {0.f,0.f,0.f,0.f};
    f32x4 H20 = {0.f,0.f,0.f,0.f}, H21 = {0.f,0.f,0.f,0.f};
    f32x4 H30 = {0.f,0.f,0.f,0.f}, H31 = {0.f,0.f,0.f,0.f};
    float* ar0 = attn_out + ((size_t)hb * SEQ + q0 + lo4) * SEQ;
    float* ar1 = ar0 + (size_t)16 * SEQ;
    float* ar2 = ar0 + (size_t)32 * SEQ;
    float* ar3 = ar0 + (size_t)48 * SEQ;
    const int src0 = lo4 + ((g & 1) * 2) * 16;
    const int src1 = src0 + 16;

    for (int c = c_lo; c < c_hi; c++) {
        const int k0 = c * 32;
        uint_t w00[2], w01[2], w10[2], w11[2];
        uint_t w20[2], w21[2], w30[2], w31[2];
        #pragma unroll
        for (int s = 0; s < 2; s++) {
            f16x8 Ak = *(const f16x8*)(Kb + (size_t)(k0 + s * 16 + lo4) * HD + g * 8);
            f32x4 Z = {0.f, 0.f, 0.f, 0.f};
            f32x4 D0 = MFMA16(Ak, Bq0, Z);
            f32x4 D1 = MFMA16(Ak, Bq1, Z);
            f32x4 D2 = MFMA16(Ak, Bq2, Z);
            f32x4 D3 = MFMA16(Ak, Bq3, Z);
            float p00 = exp2f(D0[0]) * inv0, p01 = exp2f(D0[1]) * inv0;
            float p02 = exp2f(D0[2]) * inv0, p03 = exp2f(D0[3]) * inv0;
            float p10 = exp2f(D1[0]) * inv1, p11 = exp2f(D1[1]) * inv1;
            float p12 = exp2f(D1[2]) * inv1, p13 = exp2f(D1[3]) * inv1;
            float p20 = exp2f(D2[0]) * inv2, p21 = exp2f(D2[1]) * inv2;
            float p22 = exp2f(D2[2]) * inv2, p23 = exp2f(D2[3]) * inv2;
            float p30 = exp2f(D3[0]) * inv3, p31 = exp2f(D3[1]) * inv3;
            float p32 = exp2f(D3[2]) * inv3, p33 = exp2f(D3[3]) * inv3;
            *(float4*)(ar0 + k0 + s * 16 + g * 4) = make_float4(p00, p01, p02, p03);
            *(float4*)(ar1 + k0 + s * 16 + g * 4) = make_float4(p10, p11, p12, p13);
            *(float4*)(ar2 + k0 + s * 16 + g * 4) = make_float4(p20, p21, p22, p23);
            *(float4*)(ar3 + k0 + s * 16 + g * 4) = make_float4(p30, p31, p32, p33);
            w00[s] = pk16(p00, p01); w01[s] = pk16(p02, p03);
            w10[s] = pk16(p10, p11); w11[s] = pk16(p12, p13);
            w20[s] = pk16(p20, p21); w21[s] = pk16(p22, p23);
            w30[s] = pk16(p30, p31); w31[s] = pk16(p32, p33);
        }
        union { f16x8 v; uint_t u[4]; } P0, P1, P2, P3;
        {
            uint_t a, b2;
            a = __shfl(w00[0], src0, 64); b2 = __shfl(w00[1], src0, 64); P0.u[0] = (g >= 2) ? b2 : a;
            a = __shfl(w01[0], src0, 64); b2 = __shfl(w01[1], src0, 64); P0.u[1] = (g >= 2) ? b2 : a;
            a = __shfl(w00[0], src1, 64); b2 = __shfl(w00[1], src1, 64); P0.u[2] = (g >= 2) ? b2 : a;
            a = __shfl(w01[0], src1, 64); b2 = __shfl(w01[1], src1, 64); P0.u[3] = (g >= 2) ? b2 : a;
            a = __shfl(w10[0], src0, 64); b2 = __shfl(w10[1], src0, 64); P1.u[0] = (g >= 2) ? b2 : a;
            a = __shfl(w11[0], src0, 64); b2 = __shfl(w11[1], src0, 64); P1.u[1] = (g >= 2) ? b2 : a;
            a = __shfl(w10[0], src1, 64); b2 = __shfl(w10[1], src1, 64); P1.u[2] = (g >= 2) ? b2 : a;
            a = __shfl(w11[0], src1, 64); b2 = __shfl(w11[1], src1, 64); P1.u[3] = (g >= 2) ? b2 : a;
            a = __shfl(w20[0], src0, 64); b2 = __shfl(w20[1], src0, 64); P2.u[0] = (g >= 2) ? b2 : a;
            a = __shfl(w21[0], src0, 64); b2 = __shfl(w21[1], src0, 64); P2.u[1] = (g >= 2) ? b2 : a;
            a = __shfl(w20[0], src1, 64); b2 = __shfl(w20[1], src1, 64); P2.u[2] = (g >= 2) ? b2 : a;
            a = __shfl(w21[0], src1, 64); b2 = __shfl(w21[1], src1, 64); P2.u[3] = (g >= 2) ? b2 : a;
            a = __shfl(w30[0], src0, 64); b2 = __shfl(w30[1], src0, 64); P3.u[0] = (g >= 2) ? b2 : a;
            a = __shfl(w31[0], src0, 64); b2 = __shfl(w31[1], src0, 64); P3.u[1] = (g >= 2) ? b2 : a;
            a = __shfl(w30[0], src1, 64); b2 = __shfl(w30[1], src1, 64); P3.u[2] = (g >= 2) ? b2 : a;
            a = __shfl(w31[0], src1, 64); b2 = __shfl(w31[1], src1, 64); P3.u[3] = (g >= 2) ? b2 : a;
        }
        f16x8 Av0 = *(const f16x8*)(Vb + (size_t)lo4 * SEQ + k0 + g * 8);
        f16x8 Av1 = *(const f16x8*)(Vb + (size_t)(16 + lo4) * SEQ + k0 + g * 8);
        H00 = MFMA16(Av0, P0.v, H00);
        H01 = MFMA16(Av1, P0.v, H01);
        H10 = MFMA16(Av0, P1.v, H10);
        H11 = MFMA16(Av1, P1.v, H11);
        H20 = MFMA16(Av0, P2.v, H20);
        H21 = MFMA16(Av1, P2.v, H21);
        H30 = MFMA16(Av0, P3.v, H30);
        H31 = MFMA16(Av1, P3.v, H31);
    }

    // ---- epilogue round 1: q-frags 0,1 (rows q0 .. q0+31) ----
    #pragma unroll
    for (int r = 0; r < 4; r++) {
        Hred[w][lo4][g * 4 + r]            = H00[r];
        Hred[w][lo4][16 + g * 4 + r]       = H01[r];
        Hred[w][16 + lo4][g * 4 + r]       = H10[r];
        Hred[w][16 + lo4][16 + g * 4 + r]  = H11[r];
    }
    __syncthreads();
    for (int i = tid; i < 32 * 32; i += 256) {
        int qq = i >> 5, e = i & 31;
        float sum = Hred[0][qq][e] + Hred[1][qq][e] + Hred[2][qq][e] + Hred[3][qq][e];
        heads[((size_t)hb * SEQ + q0 + qq) * HD + e] = (_Float16)sum;
    }
    __syncthreads();
    // ---- epilogue round 2: q-frags 2,3 (rows q0+32 .. q0+63) ----
    #pragma unroll
    for (int r = 0; r < 4; r++) {
        Hred[w][lo4][g * 4 + r]            = H20[r];
        Hred[w][lo4][16 + g * 4 + r]       = H21[r];
        Hred[w][16 + lo4][g * 4 + r]       = H30[r];
        Hred[w][16 + lo4][16 + g * 4 + r]  = H31[r];
    }
    __syncthreads();
    for (int i = tid; i < 32 * 32; i += 256) {
        int qq = i >> 5, e = i & 31;
        float sum = Hred[0][qq][e] + Hred[1][qq][e] + Hred[2][qq][e] + Hred[3][qq][e];
        heads[((size_t)hb * SEQ + q0 + 32 + qq) * HD + e] = (_Float16)sum;
    }
}

// ---------------------------------------------------------------------------
// Kernel 3: output projection as MFMA GEMM.
// grid 128 x 256 thr: wave = 16 rows, all 256 out cols (16 col-tiles).
// out[r][o] = sum_he H[r][he] * (WoTh + WoTl)[o][he]
// ---------------------------------------------------------------------------
__global__ __launch_bounds__(256) void out_gemm_kernel(
    const _Float16* __restrict__ Hf,
    const _Float16* __restrict__ WoTh, const _Float16* __restrict__ WoTl,
    float* __restrict__ out)
{
    const int t = threadIdx.x, w = t >> 6, l = t & 63, lo4 = l & 15, g = l >> 4;
    const int r0 = blockIdx.x * 64 + w * 16;
    const int b = r0 >> 12;
    const int sb = r0 & (SEQ - 1);

    f16x8 A[8];
    #pragma unroll
    for (int kc = 0; kc < 8; kc++)
        A[kc] = *(const f16x8*)(Hf + (((size_t)(kc * BATCH + b)) * SEQ + sb + lo4) * HD + g * 8);

    for (int ct = 0; ct < 16; ct++) {
        f32x4 acc = {0.f, 0.f, 0.f, 0.f};
        const size_t woff = (size_t)(ct * 16 + lo4) * 256 + g * 8;
        #pragma unroll
        for (int kc = 0; kc < 8; kc++) {
            acc = MFMA16(A[kc], *(const f16x8*)(WoTh + woff + kc * 32), acc);
            acc = MFMA16(A[kc], *(const f16x8*)(WoTl + woff + kc * 32), acc);
        }
        #pragma unroll
        for (int r = 0; r < 4; r++)
            out[(size_t)(r0 + g * 4 + r) * 256 + ct * 16 + lo4] = acc[r];
    }
}

extern "C" void kernel_launch(void* const* d_in, const int* in_sizes, int n_in,
                              void* d_out, int out_size, void* d_ws, size_t ws_size,
                              hipStream_t stream) {
    const float* query = (const float*)d_in[0];
    const float* wq = (const float*)d_in[1];
    const float* wk = (const float*)d_in[2];
    const float* wv = (const float*)d_in[3];
    const float* wo = (const float*)d_in[4];
    float* out = (float*)d_out;
    float* attn_out = out + (size_t)BATCH * SEQ * EMB;

    _Float16* ws = (_Float16*)d_ws;
    const size_t nx  = (size_t)BATCH * SEQ * EMB;          // 2,097,152
    const size_t per = (size_t)HEADS * BATCH * SEQ * HD;   // 2,097,152
    _Float16* Xh   = ws;
    _Float16* Xl   = Xh + nx;
    _Float16* Wth  = Xl + nx;          // 196,608
    _Float16* Wtl  = Wth + 196608;
    _Float16* WoTh = Wtl + 196608;     // 65,536
    _Float16* WoTl = WoTh + 65536;
    _Float16* Qf   = WoTl + 65536;
    _Float16* Kf   = Qf + per;
    _Float16* VT   = Kf + per;
    _Float16* Hf   = VT + per;

    prep_x_kernel<<<(int)(nx / (256 * 8)), 256, 0, stream>>>(query, Xh, Xl);
    prep_w_kernel<<<256, 256, 0, stream>>>(wq, wk, wv, wo, Wth, Wtl, WoTh, WoTl);
    qkv_gemm_kernel<<<dim3((BATCH * SEQ) / 64, 3 * HEADS), 256, 0, stream>>>(
        Xh, Xl, Wth, Wtl, Qf, Kf, VT);
    attn_kernel<<<HEADS * BATCH * (SEQ / 64), 256, 0, stream>>>(
        Qf, Kf, VT, attn_out, Hf);
    out_gemm_kernel<<<(BATCH * SEQ) / 64, 256, 0, stream>>>(Hf, WoTh, WoTl, out);
}

// Round 7
// 566.545 us; speedup vs baseline: 1.2640x; 1.2640x over previous
//
#include <hip/hip_runtime.h>
#include <math.h>

#define EMB 256
#define HEADS 8
#define HD 32
#define BATCH 2
#define SEQ 4096
#define QSCALE 0.25504672075827703f   // (1/sqrt(32)) * log2(e)  -- exp2-folded softmax scale

typedef __attribute__((ext_vector_type(8))) _Float16 f16x8;
typedef __attribute__((ext_vector_type(4))) _Float16 f16x4;
typedef __attribute__((ext_vector_type(2))) __fp16 fp16x2_native;
typedef __attribute__((ext_vector_type(4))) float f32x4;
typedef unsigned int uint_t;

__device__ __forceinline__ uint_t pk16(float a, float b) {
    union { fp16x2_native h; uint_t u; } cv;
    cv.h = __builtin_amdgcn_cvt_pkrtz(a, b);
    return cv.u;
}

#define MFMA16(A, B, C) __builtin_amdgcn_mfma_f32_16x16x32_f16(A, B, C, 0, 0, 0)

// ---------------------------------------------------------------------------
// Prep 1: query fp32 -> Xh/Xl fp16 hi/lo split.  [r=b*4096+s][256]
// ---------------------------------------------------------------------------
__global__ __launch_bounds__(256) void prep_x_kernel(
    const float* __restrict__ q, _Float16* __restrict__ Xh, _Float16* __restrict__ Xl)
{
    const int i = (blockIdx.x * 256 + threadIdx.x) * 8;
    float4 v0 = *(const float4*)(q + i);
    float4 v1 = *(const float4*)(q + i + 4);
    float xs[8] = {v0.x, v0.y, v0.z, v0.w, v1.x, v1.y, v1.z, v1.w};
    f16x8 hv, lv;
    #pragma unroll
    for (int j = 0; j < 8; j++) {
        _Float16 h = (_Float16)xs[j];
        hv[j] = h;
        lv[j] = (_Float16)(xs[j] - (float)h);
    }
    *(f16x8*)(Xh + i) = hv;
    *(f16x8*)(Xl + i) = lv;
}

// ---------------------------------------------------------------------------
// Prep 2: weights -> transposed fp16 hi/lo.
//   Wth/Wtl: [p][h][e=32][d=256], QSCALE folded into p==0 (Wq)
//   WoTh/WoTl: [o=256][he=256]
// ---------------------------------------------------------------------------
__global__ __launch_bounds__(256) void prep_w_kernel(
    const float* __restrict__ wq, const float* __restrict__ wk,
    const float* __restrict__ wv, const float* __restrict__ wo,
    _Float16* __restrict__ Wth, _Float16* __restrict__ Wtl,
    _Float16* __restrict__ WoTh, _Float16* __restrict__ WoTl)
{
    for (int t = blockIdx.x * 256 + threadIdx.x; t < 262144; t += 256 * 256) {
        if (t < 196608) {
            int d = t & 255, e = (t >> 8) & 31, ph = t >> 13;
            int p = ph >> 3, h = ph & 7;
            const float* w = (p == 0) ? wq : (p == 1 ? wk : wv);
            float val = w[h * 8192 + d * 32 + e] * ((p == 0) ? QSCALE : 1.0f);
            _Float16 hi = (_Float16)val;
            Wth[t] = hi;
            Wtl[t] = (_Float16)(val - (float)hi);
        } else {
            int t2 = t - 196608;
            int he = t2 & 255, o = t2 >> 8;
            float val = wo[(he >> 5) * 8192 + (he & 31) * 256 + o];
            _Float16 hi = (_Float16)val;
            WoTh[t2] = hi;
            WoTl[t2] = (_Float16)(val - (float)hi);
        }
    }
}

// ---------------------------------------------------------------------------
// Kernel 1: QKV projection as MFMA GEMM, no LDS staging of operands.
// grid (128, 24): x = 64-row tile (wave = 16 rows), y = p*8+h.
// D[s][e] = Xh*Wh + Xl*Wh + Xh*Wl   (fp32-grade via hi/lo split)
// Q/K: LDS-staged 64B-row writes.  V: direct VT[e][s] f16x4 writes.
// ---------------------------------------------------------------------------
__global__ __launch_bounds__(256) void qkv_gemm_kernel(
    const _Float16* __restrict__ Xh, const _Float16* __restrict__ Xl,
    const _Float16* __restrict__ Wth, const _Float16* __restrict__ Wtl,
    _Float16* __restrict__ Qf, _Float16* __restrict__ Kf, _Float16* __restrict__ VT)
{
    __shared__ _Float16 st[4][16][32];
    const int t = threadIdx.x, w = t >> 6, l = t & 63, lo4 = l & 15, g = l >> 4;
    const int tile = blockIdx.x, ph = blockIdx.y, p = ph >> 3, h = ph & 7;
    const int r0 = tile * 64 + w * 16;
    const int b = (tile * 64) >> 12;
    const int s_base = (tile * 64) & (SEQ - 1);
    const int hb = h * BATCH + b;

    f16x8 Ah[8], Al[8];
    const size_t xoff = (size_t)(r0 + lo4) * 256 + g * 8;
    #pragma unroll
    for (int kc = 0; kc < 8; kc++) {
        Ah[kc] = *(const f16x8*)(Xh + xoff + kc * 32);
        Al[kc] = *(const f16x8*)(Xl + xoff + kc * 32);
    }

    f32x4 D[2];
    #pragma unroll
    for (int ct = 0; ct < 2; ct++) {
        f32x4 acc = {0.f, 0.f, 0.f, 0.f};
        const size_t woff = (size_t)(ph * 32 + ct * 16 + lo4) * 256 + g * 8;
        #pragma unroll
        for (int kc = 0; kc < 8; kc++) {
            f16x8 Bh = *(const f16x8*)(Wth + woff + kc * 32);
            f16x8 Bl = *(const f16x8*)(Wtl + woff + kc * 32);
            acc = MFMA16(Ah[kc], Bh, acc);
            acc = MFMA16(Al[kc], Bh, acc);
            acc = MFMA16(Ah[kc], Bl, acc);
        }
        D[ct] = acc;
    }

    if (p < 2) {
        #pragma unroll
        for (int ct = 0; ct < 2; ct++)
            #pragma unroll
            for (int r = 0; r < 4; r++)
                st[w][g * 4 + r][ct * 16 + lo4] = (_Float16)D[ct][r];
        __syncthreads();
        _Float16* dst = (p == 0) ? Qf : Kf;
        const int rl = t >> 2, e8 = (t & 3) * 8;   // rl = 0..63 local row
        *(f16x8*)(dst + ((size_t)hb * SEQ + s_base + rl) * HD + e8) =
            *(f16x8*)&st[rl >> 4][rl & 15][e8];
    } else {
        #pragma unroll
        for (int ct = 0; ct < 2; ct++) {
            f16x4 v;
            #pragma unroll
            for (int r = 0; r < 4; r++) v[r] = (_Float16)D[ct][r];
            *(f16x4*)(VT + ((size_t)hb * HD + ct * 16 + lo4) * SEQ + s_base + w * 16 + g * 4) = v;
        }
    }
}

// ---------------------------------------------------------------------------
// Kernel 2: fused attention, two-pass no-max softmax (exp2-domain), fp16 MFMA.
// Round-14: q-split across WAVES (not packed into one wave -- round 6's
// mistake).  Block = 64 q-rows, wave w owns rows w*16..w*16+16 with ONE
// Q-fragment, and sweeps the FULL k-range.  All 4 waves read the same K/V
// lines each iteration -> L1 dedups to 1x per block; total logical K/V
// traffic halves vs round-0 (1.57 -> 0.79 GB).  Per-wave live state is
// ~half of round-0 (1 Bq, 2 H accs, half the shuffle network).  Row sums
// and H are wave-complete: no lred, no Hred, no LDS, no __syncthreads.
// Pass-B inner loop body is round-0's single-fragment path unchanged.
// ---------------------------------------------------------------------------
__global__ __launch_bounds__(256) void attn_kernel(
    const _Float16* __restrict__ Qf, const _Float16* __restrict__ Kf,
    const _Float16* __restrict__ VT,
    float* __restrict__ attn_out,     // [hb][q][k]
    _Float16* __restrict__ heads)     // [hb][q][e] fp16
{
    const int tid = threadIdx.x;
    const int w = tid >> 6;
    const int l = tid & 63;
    const int lo4 = l & 15;
    const int g = l >> 4;
    // XCD swizzle: 1024 blocks = 16 hb x 64 qtiles; hb%8 == bid%8 == XCD
    const int bid = blockIdx.x;
    const int xcd = bid & 7;
    const int j = bid >> 3;
    const int hb = xcd + 8 * (j >> 6);
    const int q0 = (j & 63) * 64;
    const int qw = q0 + w * 16;       // this wave's 16 q-rows

    const _Float16* Qb = Qf + (size_t)hb * SEQ * HD;
    const _Float16* Kb = Kf + (size_t)hb * SEQ * HD;
    const _Float16* Vb = VT + (size_t)hb * HD * SEQ;

    const f16x8 Bq = *(const f16x8*)(Qb + (size_t)(qw + lo4) * HD + g * 8);

    // ---------- pass A: row sums of exp2(s), full k sweep ----------
    float ls = 0.f;
    for (int c = 0; c < 128; c++) {
        const int k0 = c * 32;
        #pragma unroll
        for (int s = 0; s < 2; s++) {
            f16x8 Ak = *(const f16x8*)(Kb + (size_t)(k0 + s * 16 + lo4) * HD + g * 8);
            f32x4 D = {0.f, 0.f, 0.f, 0.f};
            D = MFMA16(Ak, Bq, D);
            ls += exp2f(D[0]) + exp2f(D[1]) + exp2f(D[2]) + exp2f(D[3]);
        }
    }
    ls += __shfl_xor(ls, 16, 64);
    ls += __shfl_xor(ls, 32, 64);
    const float inv = 1.0f / ls;      // wave-local: no LDS, no barrier

    // ---------- pass B: recompute, write probs, PV ----------
    f32x4 H0 = {0.f,0.f,0.f,0.f}, H1 = {0.f,0.f,0.f,0.f};
    float* ar = attn_out + ((size_t)hb * SEQ + qw + lo4) * SEQ;
    const int src0 = lo4 + ((g & 1) * 2) * 16;
    const int src1 = src0 + 16;

    for (int c = 0; c < 128; c++) {
        const int k0 = c * 32;
        uint_t w0[2], w1[2];
        #pragma unroll
        for (int s = 0; s < 2; s++) {
            f16x8 Ak = *(const f16x8*)(Kb + (size_t)(k0 + s * 16 + lo4) * HD + g * 8);
            f32x4 D = {0.f, 0.f, 0.f, 0.f};
            D = MFMA16(Ak, Bq, D);
            float p0 = exp2f(D[0]) * inv, p1 = exp2f(D[1]) * inv;
            float p2 = exp2f(D[2]) * inv, p3 = exp2f(D[3]) * inv;
            *(float4*)(ar + k0 + s * 16 + g * 4) = make_float4(p0, p1, p2, p3);
            w0[s] = pk16(p0, p1); w1[s] = pk16(p2, p3);
        }
        union { f16x8 v; uint_t u[4]; } P;
        {
            uint_t a, b2;
            a = __shfl(w0[0], src0, 64); b2 = __shfl(w0[1], src0, 64); P.u[0] = (g >= 2) ? b2 : a;
            a = __shfl(w1[0], src0, 64); b2 = __shfl(w1[1], src0, 64); P.u[1] = (g >= 2) ? b2 : a;
            a = __shfl(w0[0], src1, 64); b2 = __shfl(w0[1], src1, 64); P.u[2] = (g >= 2) ? b2 : a;
            a = __shfl(w1[0], src1, 64); b2 = __shfl(w1[1], src1, 64); P.u[3] = (g >= 2) ? b2 : a;
        }
        f16x8 Av0 = *(const f16x8*)(Vb + (size_t)lo4 * SEQ + k0 + g * 8);
        f16x8 Av1 = *(const f16x8*)(Vb + (size_t)(16 + lo4) * SEQ + k0 + g * 8);
        H0 = MFMA16(Av0, P.v, H0);
        H1 = MFMA16(Av1, P.v, H1);
    }

    // ---------- epilogue: wave-complete H, direct f16x4 stores ----------
    _Float16* hrow = heads + ((size_t)hb * SEQ + qw + lo4) * HD;
    f16x4 h0, h1;
    #pragma unroll
    for (int r = 0; r < 4; r++) { h0[r] = (_Float16)H0[r]; h1[r] = (_Float16)H1[r]; }
    *(f16x4*)(hrow + g * 4) = h0;
    *(f16x4*)(hrow + 16 + g * 4) = h1;
}

// ---------------------------------------------------------------------------
// Kernel 3: output projection as MFMA GEMM.
// grid 128 x 256 thr: wave = 16 rows, all 256 out cols (16 col-tiles).
// out[r][o] = sum_he H[r][he] * (WoTh + WoTl)[o][he]
// ---------------------------------------------------------------------------
__global__ __launch_bounds__(256) void out_gemm_kernel(
    const _Float16* __restrict__ Hf,
    const _Float16* __restrict__ WoTh, const _Float16* __restrict__ WoTl,
    float* __restrict__ out)
{
    const int t = threadIdx.x, w = t >> 6, l = t & 63, lo4 = l & 15, g = l >> 4;
    const int r0 = blockIdx.x * 64 + w * 16;
    const int b = r0 >> 12;
    const int sb = r0 & (SEQ - 1);

    f16x8 A[8];
    #pragma unroll
    for (int kc = 0; kc < 8; kc++)
        A[kc] = *(const f16x8*)(Hf + (((size_t)(kc * BATCH + b)) * SEQ + sb + lo4) * HD + g * 8);

    for (int ct = 0; ct < 16; ct++) {
        f32x4 acc = {0.f, 0.f, 0.f, 0.f};
        const size_t woff = (size_t)(ct * 16 + lo4) * 256 + g * 8;
        #pragma unroll
        for (int kc = 0; kc < 8; kc++) {
            acc = MFMA16(A[kc], *(const f16x8*)(WoTh + woff + kc * 32), acc);
            acc = MFMA16(A[kc], *(const f16x8*)(WoTl + woff + kc * 32), acc);
        }
        #pragma unroll
        for (int r = 0; r < 4; r++)
            out[(size_t)(r0 + g * 4 + r) * 256 + ct * 16 + lo4] = acc[r];
    }
}

extern "C" void kernel_launch(void* const* d_in, const int* in_sizes, int n_in,
                              void* d_out, int out_size, void* d_ws, size_t ws_size,
                              hipStream_t stream) {
    const float* query = (const float*)d_in[0];
    const float* wq = (const float*)d_in[1];
    const float* wk = (const float*)d_in[2];
    const float* wv = (const float*)d_in[3];
    const float* wo = (const float*)d_in[4];
    float* out = (float*)d_out;
    float* attn_out = out + (size_t)BATCH * SEQ * EMB;

    _Float16* ws = (_Float16*)d_ws;
    const size_t nx  = (size_t)BATCH * SEQ * EMB;          // 2,097,152
    const size_t per = (size_t)HEADS * BATCH * SEQ * HD;   // 2,097,152
    _Float16* Xh   = ws;
    _Float16* Xl   = Xh + nx;
    _Float16* Wth  = Xl + nx;          // 196,608
    _Float16* Wtl  = Wth + 196608;
    _Float16* WoTh = Wtl + 196608;     // 65,536
    _Float16* WoTl = WoTh + 65536;
    _Float16* Qf   = WoTl + 65536;
    _Float16* Kf   = Qf + per;
    _Float16* VT   = Kf + per;
    _Float16* Hf   = VT + per;

    prep_x_kernel<<<(int)(nx / (256 * 8)), 256, 0, stream>>>(query, Xh, Xl);
    prep_w_kernel<<<256, 256, 0, stream>>>(wq, wk, wv, wo, Wth, Wtl, WoTh, WoTl);
    qkv_gemm_kernel<<<dim3((BATCH * SEQ) / 64, 3 * HEADS), 256, 0, stream>>>(
        Xh, Xl, Wth, Wtl, Qf, Kf, VT);
    attn_kernel<<<HEADS * BATCH * (SEQ / 64), 256, 0, stream>>>(
        Qf, Kf, VT, attn_out, Hf);
    out_gemm_kernel<<<(BATCH * SEQ) / 64, 256, 0, stream>>>(Hf, WoTh, WoTl, out);
}